// Round 1
// baseline (1003.166 us; speedup 1.0000x reference)
//
#include <hip/hip_runtime.h>
#include <hip/hip_bf16.h>
#include <stdint.h>

#define BATCH 32
#define SEQ   4096
#define EMB   512
#define HEADS 8
#define HD    64
#define SCALE 0.125f   // 1/sqrt(64)

typedef __attribute__((ext_vector_type(8))) short bf16x8;
typedef __attribute__((ext_vector_type(4))) float f32x4;

__device__ __forceinline__ unsigned short f2bf(float f) {
    union { float f; unsigned int u; } v; v.f = f;
    unsigned int u = v.u;
    return (unsigned short)((u + 0x7FFFu + ((u >> 16) & 1u)) >> 16);
}
__device__ __forceinline__ float bf2f(unsigned short h) {
    union { unsigned int u; float f; } v; v.u = ((unsigned int)h) << 16;
    return v.f;
}

#define MFMA16(a, b, c) __builtin_amdgcn_mfma_f32_16x16x32_bf16((a), (b), (c), 0, 0, 0)

// ---------------------------------------------------------------------------
// K1: G[b] = x_b^T x_b (fp32), s[b] = column sums of x_b.
// grid 32*16 (b, mt, nt), block 256. BM=BN=128, BK=32, K=4096.
// Both operands transposing-staged from x (k-major) into LDS [m][k].
// ---------------------------------------------------------------------------
__global__ __launch_bounds__(256) void k1_gram(const float* __restrict__ x,
                                               float* __restrict__ G,
                                               float* __restrict__ s) {
  const int blk = blockIdx.x;
  const int b  = blk >> 4;
  const int mt = (blk >> 2) & 3;
  const int nt = blk & 3;
  const int m0 = mt * 128, n0 = nt * 128;
  const float* __restrict__ xb = x + (size_t)b * SEQ * EMB;

  __shared__ unsigned short LA[128][40];
  __shared__ unsigned short LB[128][40];
  __shared__ float SR[128][8];

  const int tid  = threadIdx.x;
  const int lane = tid & 63;
  const int wave = tid >> 6;
  const int wr = (wave >> 1) * 64;
  const int wc = (wave & 1) * 64;

  f32x4 acc[4][4];
#pragma unroll
  for (int i = 0; i < 4; ++i)
#pragma unroll
    for (int j = 0; j < 4; ++j) acc[i][j] = (f32x4){0.f, 0.f, 0.f, 0.f};

  const bool do_s = (nt == 0);
  float sacc[4] = {0.f, 0.f, 0.f, 0.f};

  const int kl = tid >> 5;   // 0..7
  const int fg = tid & 31;   // float4 group within 128-wide row

  for (int k0 = 0; k0 < SEQ; k0 += 32) {
    __syncthreads();
#pragma unroll
    for (int it = 0; it < 4; ++it) {
      const int k = kl + it * 8;
      const float4 va = *(const float4*)&xb[(size_t)(k0 + k) * EMB + m0 + fg * 4];
      LA[fg*4+0][k] = f2bf(va.x);
      LA[fg*4+1][k] = f2bf(va.y);
      LA[fg*4+2][k] = f2bf(va.z);
      LA[fg*4+3][k] = f2bf(va.w);
      if (do_s) { sacc[0]+=va.x; sacc[1]+=va.y; sacc[2]+=va.z; sacc[3]+=va.w; }
      const float4 vb = *(const float4*)&xb[(size_t)(k0 + k) * EMB + n0 + fg * 4];
      LB[fg*4+0][k] = f2bf(vb.x);
      LB[fg*4+1][k] = f2bf(vb.y);
      LB[fg*4+2][k] = f2bf(vb.z);
      LB[fg*4+3][k] = f2bf(vb.w);
    }
    __syncthreads();
    bf16x8 af[4], bfr[4];
#pragma unroll
    for (int ms = 0; ms < 4; ++ms)
      af[ms] = *(const bf16x8*)&LA[wr + ms*16 + (lane & 15)][(lane >> 4) * 8];
#pragma unroll
    for (int ns = 0; ns < 4; ++ns)
      bfr[ns] = *(const bf16x8*)&LB[wc + ns*16 + (lane & 15)][(lane >> 4) * 8];
#pragma unroll
    for (int ms = 0; ms < 4; ++ms)
#pragma unroll
      for (int ns = 0; ns < 4; ++ns)
        acc[ms][ns] = MFMA16(af[ms], bfr[ns], acc[ms][ns]);
  }

  float* __restrict__ Gb = G + (size_t)b * EMB * EMB;
#pragma unroll
  for (int ms = 0; ms < 4; ++ms)
#pragma unroll
    for (int ns = 0; ns < 4; ++ns)
#pragma unroll
      for (int r = 0; r < 4; ++r) {
        const int row = m0 + wr + ms*16 + ((lane >> 4) * 4) + r;
        const int col = n0 + wc + ns*16 + (lane & 15);
        Gb[(size_t)row * EMB + col] = acc[ms][ns][r];
      }

  if (do_s) {
    __syncthreads();
#pragma unroll
    for (int i = 0; i < 4; ++i) SR[fg*4 + i][kl] = sacc[i];
    __syncthreads();
    if (tid < 128) {
      float v = 0.f;
#pragma unroll
      for (int j = 0; j < 8; ++j) v += SR[tid][j];
      s[b * EMB + m0 + tid] = v;
    }
  }
}

// ---------------------------------------------------------------------------
// K2a: A[b] = Wq @ G_b   (fp32 out).  A direct-staged (Wq), B transposing-
// staged from fp32 G with hi/lo bf16 split (2 MFMAs per fragment).
// grid 32*16, block 256.
// ---------------------------------------------------------------------------
__global__ __launch_bounds__(256) void k2a_wqg(const float* __restrict__ Wq,
                                               const float* __restrict__ G,
                                               float* __restrict__ A) {
  const int blk = blockIdx.x;
  const int b  = blk >> 4;
  const int mt = (blk >> 2) & 3;
  const int nt = blk & 3;
  const int m0 = mt * 128, n0 = nt * 128;
  const float* __restrict__ Gb = G + (size_t)b * EMB * EMB;

  __shared__ unsigned short LA[128][40];
  __shared__ unsigned short LBhi[128][40];
  __shared__ unsigned short LBlo[128][40];

  const int tid  = threadIdx.x;
  const int lane = tid & 63;
  const int wave = tid >> 6;
  const int wr = (wave >> 1) * 64;
  const int wc = (wave & 1) * 64;

  f32x4 acc[4][4];
#pragma unroll
  for (int i = 0; i < 4; ++i)
#pragma unroll
    for (int j = 0; j < 4; ++j) acc[i][j] = (f32x4){0.f, 0.f, 0.f, 0.f};

  const int kl  = tid >> 5, fgB = tid & 31;
  const int rA  = tid >> 3, fgA = tid & 7;

  for (int k0 = 0; k0 < EMB; k0 += 32) {
    __syncthreads();
#pragma unroll
    for (int it = 0; it < 4; ++it) {   // A: Wq rows, direct
      const int r = rA + it * 32;
      const float4 v = *(const float4*)&Wq[(size_t)(m0 + r) * EMB + k0 + fgA * 4];
      ushort4 u; u.x = f2bf(v.x); u.y = f2bf(v.y); u.z = f2bf(v.z); u.w = f2bf(v.w);
      *(ushort4*)&LA[r][fgA * 4] = u;
    }
#pragma unroll
    for (int it = 0; it < 4; ++it) {   // B: G transposed, hi/lo split
      const int k = kl + it * 8;
      const float4 v = *(const float4*)&Gb[(size_t)(k0 + k) * EMB + n0 + fgB * 4];
      float vv[4] = {v.x, v.y, v.z, v.w};
#pragma unroll
      for (int i = 0; i < 4; ++i) {
        const unsigned short hi = f2bf(vv[i]);
        LBhi[fgB*4 + i][k] = hi;
        LBlo[fgB*4 + i][k] = f2bf(vv[i] - bf2f(hi));
      }
    }
    __syncthreads();
    bf16x8 af[4], bh[4], bl[4];
#pragma unroll
    for (int ms = 0; ms < 4; ++ms)
      af[ms] = *(const bf16x8*)&LA[wr + ms*16 + (lane & 15)][(lane >> 4) * 8];
#pragma unroll
    for (int ns = 0; ns < 4; ++ns) {
      bh[ns] = *(const bf16x8*)&LBhi[wc + ns*16 + (lane & 15)][(lane >> 4) * 8];
      bl[ns] = *(const bf16x8*)&LBlo[wc + ns*16 + (lane & 15)][(lane >> 4) * 8];
    }
#pragma unroll
    for (int ms = 0; ms < 4; ++ms)
#pragma unroll
      for (int ns = 0; ns < 4; ++ns) {
        acc[ms][ns] = MFMA16(af[ms], bh[ns], acc[ms][ns]);
        acc[ms][ns] = MFMA16(af[ms], bl[ns], acc[ms][ns]);
      }
  }

  float* __restrict__ Ab = A + (size_t)b * EMB * EMB;
#pragma unroll
  for (int ms = 0; ms < 4; ++ms)
#pragma unroll
    for (int ns = 0; ns < 4; ++ns)
#pragma unroll
      for (int r = 0; r < 4; ++r) {
        const int row = m0 + wr + ms*16 + ((lane >> 4) * 4) + r;
        const int col = n0 + wc + ns*16 + (lane & 15);
        Ab[(size_t)row * EMB + col] = acc[ms][ns][r];
      }
}

// ---------------------------------------------------------------------------
// K2b: per (b,h): logits = A_h @ Wk_h^T + bias terms, *1/8, softmax rows,
// store attn bf16 (64x64). A hi/lo-split-staged from fp32; Wk direct.
// grid 256 (b*8+h), block 256 (4 waves, each a 16-row strip).
// ---------------------------------------------------------------------------
__global__ __launch_bounds__(256) void k2b_logits(const float* __restrict__ A,
                                                  const float* __restrict__ Wq,
                                                  const float* __restrict__ Wk,
                                                  const float* __restrict__ bq,
                                                  const float* __restrict__ bk,
                                                  const float* __restrict__ s,
                                                  unsigned short* __restrict__ attn) {
  const int blk = blockIdx.x;
  const int b = blk >> 3;
  const int h = blk & 7;
  const float* __restrict__ Ab = A + (size_t)b * EMB * EMB + (size_t)h * HD * EMB;
  const float* __restrict__ sb = s + b * EMB;

  __shared__ unsigned short LAhi[64][40];
  __shared__ unsigned short LAlo[64][40];
  __shared__ unsigned short LB[64][40];
  __shared__ float U[HD], W[HD];

  const int tid  = threadIdx.x;
  const int lane = tid & 63;
  const int wave = tid >> 6;

  // u = Wq_h @ s, w = Wk_h @ s
  if (tid < 128) {
    const int q = tid & 63;
    const float* __restrict__ wrow = (tid < 64 ? Wq : Wk) + (size_t)(h * HD + q) * EMB;
    float a = 0.f;
    for (int i = 0; i < EMB; i += 4) {
      const float4 wv = *(const float4*)&wrow[i];
      const float4 sv = *(const float4*)&sb[i];
      a += wv.x*sv.x + wv.y*sv.y + wv.z*sv.z + wv.w*sv.w;
    }
    if (tid < 64) U[q] = a; else W[q] = a;
  }

  f32x4 acc[4];
#pragma unroll
  for (int i = 0; i < 4; ++i) acc[i] = (f32x4){0.f, 0.f, 0.f, 0.f};

  const int r8 = tid >> 3, fg8 = tid & 7;

  for (int k0 = 0; k0 < EMB; k0 += 32) {
    __syncthreads();
#pragma unroll
    for (int it = 0; it < 2; ++it) {
      const int r = r8 + it * 32;
      const float4 v = *(const float4*)&Ab[(size_t)r * EMB + k0 + fg8 * 4];
      ushort4 uh, ul;
      uh.x = f2bf(v.x); ul.x = f2bf(v.x - bf2f(uh.x));
      uh.y = f2bf(v.y); ul.y = f2bf(v.y - bf2f(uh.y));
      uh.z = f2bf(v.z); ul.z = f2bf(v.z - bf2f(uh.z));
      uh.w = f2bf(v.w); ul.w = f2bf(v.w - bf2f(uh.w));
      *(ushort4*)&LAhi[r][fg8*4] = uh;
      *(ushort4*)&LAlo[r][fg8*4] = ul;
      const float4 wv = *(const float4*)&Wk[(size_t)(h*HD + r) * EMB + k0 + fg8 * 4];
      ushort4 ub; ub.x = f2bf(wv.x); ub.y = f2bf(wv.y); ub.z = f2bf(wv.z); ub.w = f2bf(wv.w);
      *(ushort4*)&LB[r][fg8*4] = ub;
    }
    __syncthreads();
    const bf16x8 ah = *(const bf16x8*)&LAhi[wave*16 + (lane & 15)][(lane >> 4) * 8];
    const bf16x8 al = *(const bf16x8*)&LAlo[wave*16 + (lane & 15)][(lane >> 4) * 8];
#pragma unroll
    for (int ns = 0; ns < 4; ++ns) {
      const bf16x8 bb = *(const bf16x8*)&LB[ns*16 + (lane & 15)][(lane >> 4) * 8];
      acc[ns] = MFMA16(ah, bb, acc[ns]);
      acc[ns] = MFMA16(al, bb, acc[ns]);
    }
  }

  // epilogue: bias + scale + softmax over cols (axis k')
  const int colb = lane & 15;
  float bkv[4], wv_[4];
#pragma unroll
  for (int ns = 0; ns < 4; ++ns) {
    bkv[ns] = bk[h*HD + ns*16 + colb];
    wv_[ns] = W[ns*16 + colb];
  }
  unsigned short* __restrict__ ab = attn + (size_t)(b * HEADS + h) * HD * HD;
#pragma unroll
  for (int r = 0; r < 4; ++r) {
    const int row = wave*16 + ((lane >> 4) * 4) + r;
    const float bqv = bq[h*HD + row];
    const float uv  = U[row];
    float vals[4];
#pragma unroll
    for (int ns = 0; ns < 4; ++ns)
      vals[ns] = (acc[ns][r] + uv * bkv[ns] + bqv * wv_[ns] + 4096.f * bqv * bkv[ns]) * SCALE;
    float mx = fmaxf(fmaxf(vals[0], vals[1]), fmaxf(vals[2], vals[3]));
#pragma unroll
    for (int m = 1; m < 16; m <<= 1) mx = fmaxf(mx, __shfl_xor(mx, m));
    float sum = 0.f;
#pragma unroll
    for (int ns = 0; ns < 4; ++ns) { vals[ns] = expf(vals[ns] - mx); sum += vals[ns]; }
#pragma unroll
    for (int m = 1; m < 16; m <<= 1) sum += __shfl_xor(sum, m);
    const float inv = 1.f / sum;
#pragma unroll
    for (int ns = 0; ns < 4; ++ns)
      ab[(size_t)row * HD + ns*16 + colb] = f2bf(vals[ns] * inv);
  }
}

// ---------------------------------------------------------------------------
// K3a: C[b][:, h*64..] = Wo[:, h*64..] @ attn_h   (bf16 out). K=64.
// grid 32*8*4 (b,h,mt), block 256.
// ---------------------------------------------------------------------------
__global__ __launch_bounds__(256) void k3a_c(const float* __restrict__ Wo,
                                             const unsigned short* __restrict__ attn,
                                             unsigned short* __restrict__ C) {
  const int blk = blockIdx.x;
  const int b  = blk >> 5;
  const int h  = (blk >> 2) & 7;
  const int mt = blk & 3;
  const int m0 = mt * 128;

  __shared__ unsigned short LA[128][72];
  __shared__ unsigned short LB[64][72];

  const int tid  = threadIdx.x;
  const int lane = tid & 63;
  const int wave = tid >> 6;

  {
    const int r  = tid >> 4;   // 0..15
    const int fg = tid & 15;
#pragma unroll
    for (int it = 0; it < 8; ++it) {
      const int rr = r + it * 16;
      const float4 v = *(const float4*)&Wo[(size_t)(m0 + rr) * EMB + h*HD + fg * 4];
      ushort4 u; u.x = f2bf(v.x); u.y = f2bf(v.y); u.z = f2bf(v.z); u.w = f2bf(v.w);
      *(ushort4*)&LA[rr][fg * 4] = u;
    }
  }
  {
    const unsigned short* __restrict__ ab = attn + (size_t)(b * HEADS + h) * HD * HD;
#pragma unroll
    for (int it = 0; it < 16; ++it) {
      const int f  = tid + 256 * it;
      const int q  = f >> 6;
      const int kp = f & 63;
      LB[kp][q] = ab[q * HD + kp];   // transpose
    }
  }
  __syncthreads();

  f32x4 acc[2][4];
#pragma unroll
  for (int i = 0; i < 2; ++i)
#pragma unroll
    for (int j = 0; j < 4; ++j) acc[i][j] = (f32x4){0.f, 0.f, 0.f, 0.f};

#pragma unroll
  for (int kk = 0; kk < 2; ++kk) {
    bf16x8 af[2], bfr[4];
#pragma unroll
    for (int ms = 0; ms < 2; ++ms)
      af[ms] = *(const bf16x8*)&LA[wave*32 + ms*16 + (lane & 15)][kk*32 + (lane >> 4) * 8];
#pragma unroll
    for (int ns = 0; ns < 4; ++ns)
      bfr[ns] = *(const bf16x8*)&LB[ns*16 + (lane & 15)][kk*32 + (lane >> 4) * 8];
#pragma unroll
    for (int ms = 0; ms < 2; ++ms)
#pragma unroll
      for (int ns = 0; ns < 4; ++ns)
        acc[ms][ns] = MFMA16(af[ms], bfr[ns], acc[ms][ns]);
  }

  unsigned short* __restrict__ Cb = C + (size_t)b * EMB * EMB;
#pragma unroll
  for (int ms = 0; ms < 2; ++ms)
#pragma unroll
    for (int ns = 0; ns < 4; ++ns)
#pragma unroll
      for (int r = 0; r < 4; ++r) {
        const int row = m0 + wave*32 + ms*16 + ((lane >> 4) * 4) + r;
        const int col = h*HD + ns*16 + (lane & 15);
        Cb[(size_t)row * EMB + col] = f2bf(acc[ms][ns][r]);
      }
}

// ---------------------------------------------------------------------------
// K3b: D[b] = C_b @ Wv  (bf16 out, row-major [e'][i]). grid 32*16.
// A = C (bf16) direct-staged; B = Wv (fp32) transposing-staged.
// ---------------------------------------------------------------------------
__global__ __launch_bounds__(256) void k3b_d(const unsigned short* __restrict__ C,
                                             const float* __restrict__ Wv,
                                             unsigned short* __restrict__ D) {
  const int blk = blockIdx.x;
  const int b  = blk >> 4;
  const int mt = (blk >> 2) & 3;
  const int nt = blk & 3;
  const int m0 = mt * 128, n0 = nt * 128;
  const unsigned short* __restrict__ Cb = C + (size_t)b * EMB * EMB;

  __shared__ unsigned short LA[128][40];
  __shared__ unsigned short LB[128][40];

  const int tid  = threadIdx.x;
  const int lane = tid & 63;
  const int wave = tid >> 6;
  const int wr = (wave >> 1) * 64;
  const int wc = (wave & 1) * 64;

  f32x4 acc[4][4];
#pragma unroll
  for (int i = 0; i < 4; ++i)
#pragma unroll
    for (int j = 0; j < 4; ++j) acc[i][j] = (f32x4){0.f, 0.f, 0.f, 0.f};

  const int kl = tid >> 5, fgB = tid & 31;
  const int rA = tid >> 3, fgA = tid & 7;

  for (int k0 = 0; k0 < EMB; k0 += 32) {
    __syncthreads();
#pragma unroll
    for (int it = 0; it < 4; ++it) {
      const int r = rA + it * 32;
      *(ushort4*)&LA[r][fgA*4] = *(const ushort4*)&Cb[(size_t)(m0 + r) * EMB + k0 + fgA * 4];
    }
#pragma unroll
    for (int it = 0; it < 4; ++it) {
      const int k = kl + it * 8;
      const float4 v = *(const float4*)&Wv[(size_t)(k0 + k) * EMB + n0 + fgB * 4];
      LB[fgB*4+0][k] = f2bf(v.x);
      LB[fgB*4+1][k] = f2bf(v.y);
      LB[fgB*4+2][k] = f2bf(v.z);
      LB[fgB*4+3][k] = f2bf(v.w);
    }
    __syncthreads();
    bf16x8 af[4], bfr[4];
#pragma unroll
    for (int ms = 0; ms < 4; ++ms)
      af[ms] = *(const bf16x8*)&LA[wr + ms*16 + (lane & 15)][(lane >> 4) * 8];
#pragma unroll
    for (int ns = 0; ns < 4; ++ns)
      bfr[ns] = *(const bf16x8*)&LB[wc + ns*16 + (lane & 15)][(lane >> 4) * 8];
#pragma unroll
    for (int ms = 0; ms < 4; ++ms)
#pragma unroll
      for (int ns = 0; ns < 4; ++ns)
        acc[ms][ns] = MFMA16(af[ms], bfr[ns], acc[ms][ns]);
  }

  unsigned short* __restrict__ Db = D + (size_t)b * EMB * EMB;
#pragma unroll
  for (int ms = 0; ms < 4; ++ms)
#pragma unroll
    for (int ns = 0; ns < 4; ++ns)
#pragma unroll
      for (int r = 0; r < 4; ++r) {
        const int row = m0 + wr + ms*16 + ((lane >> 4) * 4) + r;
        const int col = n0 + wc + ns*16 + (lane & 15);
        Db[(size_t)row * EMB + col] = f2bf(acc[ms][ns][r]);
      }
}

// ---------------------------------------------------------------------------
// K3c: e[b] = C_b @ bv + bo.  grid 32*16 (32 rows each), block 256.
// ---------------------------------------------------------------------------
__global__ __launch_bounds__(256) void k3c_e(const unsigned short* __restrict__ C,
                                             const float* __restrict__ bv,
                                             const float* __restrict__ bo,
                                             float* __restrict__ evec) {
  const int blk = blockIdx.x;
  const int b = blk >> 4;
  const int g = blk & 15;
  const int tid  = threadIdx.x;
  const int lane = tid & 63;
  const int wave = tid >> 6;

  __shared__ float BV[EMB];
  for (int i = tid; i < EMB; i += 256) BV[i] = bv[i];
  __syncthreads();

  const unsigned short* __restrict__ Cb = C + (size_t)b * EMB * EMB;
#pragma unroll
  for (int p = 0; p < 8; ++p) {
    const int row = g*32 + wave*8 + p;
    const unsigned short* cr = &Cb[(size_t)row * EMB + lane * 8];
    const float* bvp = &BV[lane * 8];
    ushort4 v0 = *(const ushort4*)&cr[0];
    ushort4 v1 = *(const ushort4*)&cr[4];
    float a = bf2f(v0.x)*bvp[0] + bf2f(v0.y)*bvp[1] + bf2f(v0.z)*bvp[2] + bf2f(v0.w)*bvp[3]
            + bf2f(v1.x)*bvp[4] + bf2f(v1.y)*bvp[5] + bf2f(v1.z)*bvp[6] + bf2f(v1.w)*bvp[7];
#pragma unroll
    for (int m = 1; m < 64; m <<= 1) a += __shfl_xor(a, m);
    if (lane == 0) evec[b * EMB + row] = a + bo[row];
  }
}

// ---------------------------------------------------------------------------
// K4: out[b] = x_b @ D_b^T + e_b.  grid 32*32*4, block 256. BT-gemm, K=512.
// ---------------------------------------------------------------------------
__global__ __launch_bounds__(256) void k4_out(const float* __restrict__ x,
                                              const unsigned short* __restrict__ D,
                                              const float* __restrict__ evec,
                                              float* __restrict__ out) {
  const int blk = blockIdx.x;
  const int b  = blk >> 7;
  const int mt = (blk >> 2) & 31;
  const int nt = blk & 3;
  const int m0 = mt * 128, n0 = nt * 128;
  const float* __restrict__ xb = x + (size_t)b * SEQ * EMB;
  const unsigned short* __restrict__ Db = D + (size_t)b * EMB * EMB;

  __shared__ unsigned short LA[128][40];
  __shared__ unsigned short LB[128][40];

  const int tid  = threadIdx.x;
  const int lane = tid & 63;
  const int wave = tid >> 6;
  const int wr = (wave >> 1) * 64;
  const int wc = (wave & 1) * 64;

  f32x4 acc[4][4];
#pragma unroll
  for (int i = 0; i < 4; ++i)
#pragma unroll
    for (int j = 0; j < 4; ++j) acc[i][j] = (f32x4){0.f, 0.f, 0.f, 0.f};

  const int rA = tid >> 3, fgA = tid & 7;

  for (int k0 = 0; k0 < EMB; k0 += 32) {
    __syncthreads();
#pragma unroll
    for (int it = 0; it < 4; ++it) {
      const int r = rA + it * 32;
      const float4 v = *(const float4*)&xb[(size_t)(m0 + r) * EMB + k0 + fgA * 4];
      ushort4 u; u.x = f2bf(v.x); u.y = f2bf(v.y); u.z = f2bf(v.z); u.w = f2bf(v.w);
      *(ushort4*)&LA[r][fgA * 4] = u;
      *(ushort4*)&LB[r][fgA * 4] = *(const ushort4*)&Db[(size_t)(n0 + r) * EMB + k0 + fgA * 4];
    }
    __syncthreads();
    bf16x8 af[4], bfr[4];
#pragma unroll
    for (int ms = 0; ms < 4; ++ms)
      af[ms] = *(const bf16x8*)&LA[wr + ms*16 + (lane & 15)][(lane >> 4) * 8];
#pragma unroll
    for (int ns = 0; ns < 4; ++ns)
      bfr[ns] = *(const bf16x8*)&LB[wc + ns*16 + (lane & 15)][(lane >> 4) * 8];
#pragma unroll
    for (int ms = 0; ms < 4; ++ms)
#pragma unroll
      for (int ns = 0; ns < 4; ++ns)
        acc[ms][ns] = MFMA16(af[ms], bfr[ns], acc[ms][ns]);
  }

#pragma unroll
  for (int ms = 0; ms < 4; ++ms)
#pragma unroll
    for (int ns = 0; ns < 4; ++ns)
#pragma unroll
      for (int r = 0; r < 4; ++r) {
        const int row = m0 + wr + ms*16 + ((lane >> 4) * 4) + r;
        const int col = n0 + wc + ns*16 + (lane & 15);
        out[((size_t)b * SEQ + row) * EMB + col] = acc[ms][ns][r] + evec[b * EMB + col];
      }
}

// ---------------------------------------------------------------------------
extern "C" void kernel_launch(void* const* d_in, const int* in_sizes, int n_in,
                              void* d_out, int out_size, void* d_ws, size_t ws_size,
                              hipStream_t stream) {
  (void)in_sizes; (void)n_in; (void)out_size; (void)ws_size;
  const float* x  = (const float*)d_in[0];
  const float* Wq = (const float*)d_in[1];
  const float* bq = (const float*)d_in[2];
  const float* Wk = (const float*)d_in[3];
  const float* bk = (const float*)d_in[4];
  const float* Wv = (const float*)d_in[5];
  const float* bv = (const float*)d_in[6];
  const float* Wo = (const float*)d_in[7];
  const float* bo = (const float*)d_in[8];
  float* out = (float*)d_out;

  char* ws = (char*)d_ws;
  // Region layout (bytes). G dies after k2a; C/D reuse its region.
  float*          G    = (float*)(ws + 0);                     // 32 MB
  unsigned short* Cm   = (unsigned short*)(ws + 0);            // 16 MB (after G dead)
  unsigned short* Dm   = (unsigned short*)(ws + (16u << 20));  // 16 MB
  float*          A    = (float*)(ws + (32u << 20));           // 32 MB
  unsigned short* attn = (unsigned short*)(ws + (64u << 20));  // 2 MB
  float*          sv   = (float*)(ws + (66u << 20));           // 64 KB
  float*          ev   = (float*)(ws + (66u << 20) + (64u << 10)); // 64 KB

  hipLaunchKernelGGL(k1_gram,    dim3(BATCH * 16),  dim3(256), 0, stream, x, G, sv);
  hipLaunchKernelGGL(k2a_wqg,    dim3(BATCH * 16),  dim3(256), 0, stream, Wq, G, A);
  hipLaunchKernelGGL(k2b_logits, dim3(BATCH * 8),   dim3(256), 0, stream, A, Wq, Wk, bq, bk, sv, attn);
  hipLaunchKernelGGL(k3a_c,      dim3(BATCH * 32),  dim3(256), 0, stream, Wo, attn, Cm);
  hipLaunchKernelGGL(k3b_d,      dim3(BATCH * 16),  dim3(256), 0, stream, Cm, Wv, Dm);
  hipLaunchKernelGGL(k3c_e,      dim3(BATCH * 16),  dim3(256), 0, stream, Cm, bv, bo, ev);
  hipLaunchKernelGGL(k4_out,     dim3(BATCH * 128), dim3(256), 0, stream, x, Dm, ev, out);
}

// Round 2
// 562.539 us; speedup vs baseline: 1.7833x; 1.7833x over previous
//
#include <hip/hip_runtime.h>
#include <hip/hip_bf16.h>
#include <stdint.h>

#define BATCH 32
#define SEQ   4096
#define EMB   512
#define HEADS 8
#define HD    64
#define SCALE 0.125f   // 1/sqrt(64)

typedef __attribute__((ext_vector_type(8))) short bf16x8;
typedef __attribute__((ext_vector_type(4))) float f32x4;

__device__ __forceinline__ unsigned short f2bf(float f) {
    union { float f; unsigned int u; } v; v.f = f;
    unsigned int u = v.u;
    return (unsigned short)((u + 0x7FFFu + ((u >> 16) & 1u)) >> 16);
}
__device__ __forceinline__ float bf2f(unsigned short h) {
    union { unsigned int u; float f; } v; v.u = ((unsigned int)h) << 16;
    return v.f;
}
// HW packed fp32->bf16 (RNE): lo -> bits[15:0], hi -> bits[31:16]
__device__ __forceinline__ unsigned int cvtpk(float lo, float hi) {
    unsigned int r;
    asm("v_cvt_pk_bf16_f32 %0, %1, %2" : "=v"(r) : "v"(lo), "v"(hi));
    return r;
}
__device__ __forceinline__ float lo_as_f(unsigned int p) {
    union { unsigned int u; float f; } v; v.u = p << 16; return v.f;
}
__device__ __forceinline__ float hi_as_f(unsigned int p) {
    union { unsigned int u; float f; } v; v.u = p & 0xFFFF0000u; return v.f;
}

#define MFMA16(a, b, c) __builtin_amdgcn_mfma_f32_16x16x32_bf16((a), (b), (c), 0, 0, 0)

// ---------------------------------------------------------------------------
// K1: G[b] = x_b^T x_b (fp32), s[b] = column sums of x_b (on diagonal blocks).
// grid 32*16 (b, mt, nt), block 256. BM=BN=128, BK=32, K=4096.
// Register-transpose staging: thread loads 4 float4 from 4 consecutive k-rows
// (coalesced), transposes in registers, cvt_pk -> b64 LDS writes.
// LDS layout: [e>>2][e&3][k] ushort, row (e>>2) stride 136 ushort (272 B):
//   b128 frag reads ~2-way conflict, b64 writes ~4-way.
// Diagonal blocks (mt==nt) stage only LA and read B-frags from it.
// ---------------------------------------------------------------------------
__global__ __launch_bounds__(256) void k1_gram(const float* __restrict__ x,
                                               float* __restrict__ G,
                                               float* __restrict__ s) {
  const int blk = blockIdx.x;
  const int b  = blk >> 4;
  const int mt = (blk >> 2) & 3;
  const int nt = blk & 3;
  const int m0 = mt * 128, n0 = nt * 128;
  const bool diag = (mt == nt);
  const float* __restrict__ xb = x + (size_t)b * SEQ * EMB;

  __shared__ unsigned short LA[32 * 136];
  __shared__ unsigned short LB[32 * 136];
  __shared__ float SR[128][8];

  const int tid  = threadIdx.x;
  const int lane = tid & 63;
  const int wave = tid >> 6;
  const int wr = (wave >> 1) * 64;
  const int wc = (wave & 1) * 64;

  const int fg   = tid & 31;   // e-group: e = fg*4 + i
  const int kgrp = tid >> 5;   // k-group: k = kgrp*4 + j

  f32x4 acc[4][4];
#pragma unroll
  for (int i = 0; i < 4; ++i)
#pragma unroll
    for (int j = 0; j < 4; ++j) acc[i][j] = (f32x4){0.f, 0.f, 0.f, 0.f};

  float sacc[4] = {0.f, 0.f, 0.f, 0.f};
  const unsigned short* __restrict__ Bsrc = diag ? LA : LB;

  union F4 { float4 v; float f[4]; };

  for (int k0 = 0; k0 < SEQ; k0 += 32) {
    __syncthreads();
    {
      const float* pA = &xb[(size_t)(k0 + kgrp * 4) * EMB + m0 + fg * 4];
      F4 a0, a1, a2, a3;
      a0.v = *(const float4*)pA;
      a1.v = *(const float4*)(pA + EMB);
      a2.v = *(const float4*)(pA + 2 * EMB);
      a3.v = *(const float4*)(pA + 3 * EMB);
#pragma unroll
      for (int i = 0; i < 4; ++i) {
        const float e0 = a0.f[i], e1 = a1.f[i], e2 = a2.f[i], e3 = a3.f[i];
        if (diag) sacc[i] += (e0 + e1) + (e2 + e3);
        uint2 w; w.x = cvtpk(e0, e1); w.y = cvtpk(e2, e3);
        *(uint2*)&LA[fg * 136 + i * 32 + kgrp * 4] = w;
      }
      if (!diag) {
        const float* pB = &xb[(size_t)(k0 + kgrp * 4) * EMB + n0 + fg * 4];
        F4 b0, b1, b2, b3;
        b0.v = *(const float4*)pB;
        b1.v = *(const float4*)(pB + EMB);
        b2.v = *(const float4*)(pB + 2 * EMB);
        b3.v = *(const float4*)(pB + 3 * EMB);
#pragma unroll
        for (int i = 0; i < 4; ++i) {
          uint2 w; w.x = cvtpk(b0.f[i], b1.f[i]); w.y = cvtpk(b2.f[i], b3.f[i]);
          *(uint2*)&LB[fg * 136 + i * 32 + kgrp * 4] = w;
        }
      }
    }
    __syncthreads();
    bf16x8 af[4], bfr[4];
    const int er = lane & 15, kb = (lane >> 4) * 8;
#pragma unroll
    for (int ms = 0; ms < 4; ++ms) {
      const int e = wr + ms * 16 + er;
      af[ms] = *(const bf16x8*)&LA[(e >> 2) * 136 + (e & 3) * 32 + kb];
    }
#pragma unroll
    for (int ns = 0; ns < 4; ++ns) {
      const int e = wc + ns * 16 + er;
      bfr[ns] = *(const bf16x8*)&Bsrc[(e >> 2) * 136 + (e & 3) * 32 + kb];
    }
#pragma unroll
    for (int ms = 0; ms < 4; ++ms)
#pragma unroll
      for (int ns = 0; ns < 4; ++ns)
        acc[ms][ns] = MFMA16(af[ms], bfr[ns], acc[ms][ns]);
  }

  float* __restrict__ Gb = G + (size_t)b * EMB * EMB;
#pragma unroll
  for (int ms = 0; ms < 4; ++ms)
#pragma unroll
    for (int ns = 0; ns < 4; ++ns)
#pragma unroll
      for (int r = 0; r < 4; ++r) {
        const int row = m0 + wr + ms * 16 + ((lane >> 4) * 4) + r;
        const int col = n0 + wc + ns * 16 + (lane & 15);
        Gb[(size_t)row * EMB + col] = acc[ms][ns][r];
      }

  if (diag) {
    __syncthreads();
#pragma unroll
    for (int i = 0; i < 4; ++i) SR[fg * 4 + i][kgrp] = sacc[i];
    __syncthreads();
    if (tid < 128) {
      float v = 0.f;
#pragma unroll
      for (int j = 0; j < 8; ++j) v += SR[tid][j];
      s[b * EMB + m0 + tid] = v;
    }
  }
}

// ---------------------------------------------------------------------------
// K2a: A[b] = Wq @ G_b (fp32 out). A direct-staged (Wq, cvt_pk). B operand
// uses G's SYMMETRY: B[n][k] = G[n][k] -> direct-staged from G rows
// (vectorized, no transpose) with hi/lo bf16 split. grid 32*16, block 256.
// ---------------------------------------------------------------------------
__global__ __launch_bounds__(256) void k2a_wqg(const float* __restrict__ Wq,
                                               const float* __restrict__ G,
                                               float* __restrict__ A) {
  const int blk = blockIdx.x;
  const int b  = blk >> 4;
  const int mt = (blk >> 2) & 3;
  const int nt = blk & 3;
  const int m0 = mt * 128, n0 = nt * 128;
  const float* __restrict__ Gb = G + (size_t)b * EMB * EMB;

  __shared__ unsigned short LA[128][40];
  __shared__ unsigned short LBhi[128][40];
  __shared__ unsigned short LBlo[128][40];

  const int tid  = threadIdx.x;
  const int lane = tid & 63;
  const int wave = tid >> 6;
  const int wr = (wave >> 1) * 64;
  const int wc = (wave & 1) * 64;

  f32x4 acc[4][4];
#pragma unroll
  for (int i = 0; i < 4; ++i)
#pragma unroll
    for (int j = 0; j < 4; ++j) acc[i][j] = (f32x4){0.f, 0.f, 0.f, 0.f};

  const int rA = tid >> 3, fgA = tid & 7;

  for (int k0 = 0; k0 < EMB; k0 += 32) {
    __syncthreads();
#pragma unroll
    for (int it = 0; it < 4; ++it) {   // A: Wq rows, direct
      const int r = rA + it * 32;
      const float4 v = *(const float4*)&Wq[(size_t)(m0 + r) * EMB + k0 + fgA * 4];
      uint2 u; u.x = cvtpk(v.x, v.y); u.y = cvtpk(v.z, v.w);
      *(uint2*)&LA[r][fgA * 4] = u;
    }
#pragma unroll
    for (int it = 0; it < 4; ++it) {   // B: G rows (symmetric), hi/lo split
      const int r = rA + it * 32;
      const float4 v = *(const float4*)&Gb[(size_t)(n0 + r) * EMB + k0 + fgA * 4];
      uint2 h; h.x = cvtpk(v.x, v.y); h.y = cvtpk(v.z, v.w);
      uint2 l;
      l.x = cvtpk(v.x - lo_as_f(h.x), v.y - hi_as_f(h.x));
      l.y = cvtpk(v.z - lo_as_f(h.y), v.w - hi_as_f(h.y));
      *(uint2*)&LBhi[r][fgA * 4] = h;
      *(uint2*)&LBlo[r][fgA * 4] = l;
    }
    __syncthreads();
    bf16x8 af[4], bh[4], bl[4];
#pragma unroll
    for (int ms = 0; ms < 4; ++ms)
      af[ms] = *(const bf16x8*)&LA[wr + ms*16 + (lane & 15)][(lane >> 4) * 8];
#pragma unroll
    for (int ns = 0; ns < 4; ++ns) {
      bh[ns] = *(const bf16x8*)&LBhi[wc + ns*16 + (lane & 15)][(lane >> 4) * 8];
      bl[ns] = *(const bf16x8*)&LBlo[wc + ns*16 + (lane & 15)][(lane >> 4) * 8];
    }
#pragma unroll
    for (int ms = 0; ms < 4; ++ms)
#pragma unroll
      for (int ns = 0; ns < 4; ++ns) {
        acc[ms][ns] = MFMA16(af[ms], bh[ns], acc[ms][ns]);
        acc[ms][ns] = MFMA16(af[ms], bl[ns], acc[ms][ns]);
      }
  }

  float* __restrict__ Ab = A + (size_t)b * EMB * EMB;
#pragma unroll
  for (int ms = 0; ms < 4; ++ms)
#pragma unroll
    for (int ns = 0; ns < 4; ++ns)
#pragma unroll
      for (int r = 0; r < 4; ++r) {
        const int row = m0 + wr + ms*16 + ((lane >> 4) * 4) + r;
        const int col = n0 + wc + ns*16 + (lane & 15);
        Ab[(size_t)row * EMB + col] = acc[ms][ns][r];
      }
}

// ---------------------------------------------------------------------------
// K2b: per (b,h): logits = A_h @ Wk_h^T + bias terms, *1/8, softmax rows,
// store attn bf16 (64x64). grid 256 (b*8+h), block 256.
// ---------------------------------------------------------------------------
__global__ __launch_bounds__(256) void k2b_logits(const float* __restrict__ A,
                                                  const float* __restrict__ Wq,
                                                  const float* __restrict__ Wk,
                                                  const float* __restrict__ bq,
                                                  const float* __restrict__ bk,
                                                  const float* __restrict__ s,
                                                  unsigned short* __restrict__ attn) {
  const int blk = blockIdx.x;
  const int b = blk >> 3;
  const int h = blk & 7;
  const float* __restrict__ Ab = A + (size_t)b * EMB * EMB + (size_t)h * HD * EMB;
  const float* __restrict__ sb = s + b * EMB;

  __shared__ unsigned short LAhi[64][40];
  __shared__ unsigned short LAlo[64][40];
  __shared__ unsigned short LB[64][40];
  __shared__ float U[HD], W[HD];

  const int tid  = threadIdx.x;
  const int lane = tid & 63;
  const int wave = tid >> 6;

  // u = Wq_h @ s, w = Wk_h @ s
  if (tid < 128) {
    const int q = tid & 63;
    const float* __restrict__ wrow = (tid < 64 ? Wq : Wk) + (size_t)(h * HD + q) * EMB;
    float a = 0.f;
    for (int i = 0; i < EMB; i += 4) {
      const float4 wv = *(const float4*)&wrow[i];
      const float4 sv = *(const float4*)&sb[i];
      a += wv.x*sv.x + wv.y*sv.y + wv.z*sv.z + wv.w*sv.w;
    }
    if (tid < 64) U[q] = a; else W[q] = a;
  }

  f32x4 acc[4];
#pragma unroll
  for (int i = 0; i < 4; ++i) acc[i] = (f32x4){0.f, 0.f, 0.f, 0.f};

  const int r8 = tid >> 3, fg8 = tid & 7;

  for (int k0 = 0; k0 < EMB; k0 += 32) {
    __syncthreads();
#pragma unroll
    for (int it = 0; it < 2; ++it) {
      const int r = r8 + it * 32;
      const float4 v = *(const float4*)&Ab[(size_t)r * EMB + k0 + fg8 * 4];
      uint2 h2; h2.x = cvtpk(v.x, v.y); h2.y = cvtpk(v.z, v.w);
      uint2 l2;
      l2.x = cvtpk(v.x - lo_as_f(h2.x), v.y - hi_as_f(h2.x));
      l2.y = cvtpk(v.z - lo_as_f(h2.y), v.w - hi_as_f(h2.y));
      *(uint2*)&LAhi[r][fg8*4] = h2;
      *(uint2*)&LAlo[r][fg8*4] = l2;
      const float4 wv = *(const float4*)&Wk[(size_t)(h*HD + r) * EMB + k0 + fg8 * 4];
      uint2 ub; ub.x = cvtpk(wv.x, wv.y); ub.y = cvtpk(wv.z, wv.w);
      *(uint2*)&LB[r][fg8*4] = ub;
    }
    __syncthreads();
    const bf16x8 ah = *(const bf16x8*)&LAhi[wave*16 + (lane & 15)][(lane >> 4) * 8];
    const bf16x8 al = *(const bf16x8*)&LAlo[wave*16 + (lane & 15)][(lane >> 4) * 8];
#pragma unroll
    for (int ns = 0; ns < 4; ++ns) {
      const bf16x8 bb = *(const bf16x8*)&LB[ns*16 + (lane & 15)][(lane >> 4) * 8];
      acc[ns] = MFMA16(ah, bb, acc[ns]);
      acc[ns] = MFMA16(al, bb, acc[ns]);
    }
  }

  // epilogue: bias + scale + softmax over cols (axis k')
  const int colb = lane & 15;
  float bkv[4], wv_[4];
#pragma unroll
  for (int ns = 0; ns < 4; ++ns) {
    bkv[ns] = bk[h*HD + ns*16 + colb];
    wv_[ns] = W[ns*16 + colb];
  }
  unsigned short* __restrict__ ab = attn + (size_t)(b * HEADS + h) * HD * HD;
#pragma unroll
  for (int r = 0; r < 4; ++r) {
    const int row = wave*16 + ((lane >> 4) * 4) + r;
    const float bqv = bq[h*HD + row];
    const float uv  = U[row];
    float vals[4];
#pragma unroll
    for (int ns = 0; ns < 4; ++ns)
      vals[ns] = (acc[ns][r] + uv * bkv[ns] + bqv * wv_[ns] + 4096.f * bqv * bkv[ns]) * SCALE;
    float mx = fmaxf(fmaxf(vals[0], vals[1]), fmaxf(vals[2], vals[3]));
#pragma unroll
    for (int m = 1; m < 16; m <<= 1) mx = fmaxf(mx, __shfl_xor(mx, m));
    float sum = 0.f;
#pragma unroll
    for (int ns = 0; ns < 4; ++ns) { vals[ns] = expf(vals[ns] - mx); sum += vals[ns]; }
#pragma unroll
    for (int m = 1; m < 16; m <<= 1) sum += __shfl_xor(sum, m);
    const float inv = 1.f / sum;
#pragma unroll
    for (int ns = 0; ns < 4; ++ns)
      ab[(size_t)row * HD + ns*16 + colb] = f2bf(vals[ns] * inv);
  }
}

// ---------------------------------------------------------------------------
// K3a: C[b][:, h*64..] = Wo[:, h*64..] @ attn_h   (bf16 out). K=64.
// grid 32*8*4 (b,h,mt), block 256.
// ---------------------------------------------------------------------------
__global__ __launch_bounds__(256) void k3a_c(const float* __restrict__ Wo,
                                             const unsigned short* __restrict__ attn,
                                             unsigned short* __restrict__ C) {
  const int blk = blockIdx.x;
  const int b  = blk >> 5;
  const int h  = (blk >> 2) & 7;
  const int mt = blk & 3;
  const int m0 = mt * 128;

  __shared__ unsigned short LA[128][72];
  __shared__ unsigned short LB[64][72];

  const int tid  = threadIdx.x;
  const int lane = tid & 63;
  const int wave = tid >> 6;

  {
    const int r  = tid >> 4;   // 0..15
    const int fg = tid & 15;
#pragma unroll
    for (int it = 0; it < 8; ++it) {
      const int rr = r + it * 16;
      const float4 v = *(const float4*)&Wo[(size_t)(m0 + rr) * EMB + h*HD + fg * 4];
      uint2 u; u.x = cvtpk(v.x, v.y); u.y = cvtpk(v.z, v.w);
      *(uint2*)&LA[rr][fg * 4] = u;
    }
  }
  {
    const unsigned short* __restrict__ ab = attn + (size_t)(b * HEADS + h) * HD * HD;
#pragma unroll
    for (int it = 0; it < 16; ++it) {
      const int f  = tid + 256 * it;
      const int q  = f >> 6;
      const int kp = f & 63;
      LB[kp][q] = ab[q * HD + kp];   // transpose
    }
  }
  __syncthreads();

  f32x4 acc[2][4];
#pragma unroll
  for (int i = 0; i < 2; ++i)
#pragma unroll
    for (int j = 0; j < 4; ++j) acc[i][j] = (f32x4){0.f, 0.f, 0.f, 0.f};

#pragma unroll
  for (int kk = 0; kk < 2; ++kk) {
    bf16x8 af[2], bfr[4];
#pragma unroll
    for (int ms = 0; ms < 2; ++ms)
      af[ms] = *(const bf16x8*)&LA[wave*32 + ms*16 + (lane & 15)][kk*32 + (lane >> 4) * 8];
#pragma unroll
    for (int ns = 0; ns < 4; ++ns)
      bfr[ns] = *(const bf16x8*)&LB[ns*16 + (lane & 15)][kk*32 + (lane >> 4) * 8];
#pragma unroll
    for (int ms = 0; ms < 2; ++ms)
#pragma unroll
      for (int ns = 0; ns < 4; ++ns)
        acc[ms][ns] = MFMA16(af[ms], bfr[ns], acc[ms][ns]);
  }

  unsigned short* __restrict__ Cb = C + (size_t)b * EMB * EMB;
#pragma unroll
  for (int ms = 0; ms < 2; ++ms)
#pragma unroll
    for (int ns = 0; ns < 4; ++ns)
#pragma unroll
      for (int r = 0; r < 4; ++r) {
        const int row = m0 + wave*32 + ms*16 + ((lane >> 4) * 4) + r;
        const int col = h*HD + ns*16 + (lane & 15);
        Cb[(size_t)row * EMB + col] = f2bf(acc[ms][ns][r]);
      }
}

// ---------------------------------------------------------------------------
// K3b: D[b] = C_b @ Wv  (bf16 out). grid 32*16, block 256.
// ---------------------------------------------------------------------------
__global__ __launch_bounds__(256) void k3b_d(const unsigned short* __restrict__ C,
                                             const float* __restrict__ Wv,
                                             unsigned short* __restrict__ D) {
  const int blk = blockIdx.x;
  const int b  = blk >> 4;
  const int mt = (blk >> 2) & 3;
  const int nt = blk & 3;
  const int m0 = mt * 128, n0 = nt * 128;
  const unsigned short* __restrict__ Cb = C + (size_t)b * EMB * EMB;

  __shared__ unsigned short LA[128][40];
  __shared__ unsigned short LB[128][40];

  const int tid  = threadIdx.x;
  const int lane = tid & 63;
  const int wave = tid >> 6;
  const int wr = (wave >> 1) * 64;
  const int wc = (wave & 1) * 64;

  f32x4 acc[4][4];
#pragma unroll
  for (int i = 0; i < 4; ++i)
#pragma unroll
    for (int j = 0; j < 4; ++j) acc[i][j] = (f32x4){0.f, 0.f, 0.f, 0.f};

  const int kl = tid >> 5, fgB = tid & 31;
  const int rA = tid >> 3, fgA = tid & 7;

  for (int k0 = 0; k0 < EMB; k0 += 32) {
    __syncthreads();
#pragma unroll
    for (int it = 0; it < 4; ++it) {
      const int r = rA + it * 32;
      *(ushort4*)&LA[r][fgA*4] = *(const ushort4*)&Cb[(size_t)(m0 + r) * EMB + k0 + fgA * 4];
    }
#pragma unroll
    for (int it = 0; it < 4; ++it) {
      const int k = kl + it * 8;
      const float4 v = *(const float4*)&Wv[(size_t)(k0 + k) * EMB + n0 + fgB * 4];
      LB[fgB*4+0][k] = f2bf(v.x);
      LB[fgB*4+1][k] = f2bf(v.y);
      LB[fgB*4+2][k] = f2bf(v.z);
      LB[fgB*4+3][k] = f2bf(v.w);
    }
    __syncthreads();
    bf16x8 af[4], bfr[4];
#pragma unroll
    for (int ms = 0; ms < 4; ++ms)
      af[ms] = *(const bf16x8*)&LA[wr + ms*16 + (lane & 15)][(lane >> 4) * 8];
#pragma unroll
    for (int ns = 0; ns < 4; ++ns)
      bfr[ns] = *(const bf16x8*)&LB[wc + ns*16 + (lane & 15)][(lane >> 4) * 8];
#pragma unroll
    for (int ms = 0; ms < 4; ++ms)
#pragma unroll
      for (int ns = 0; ns < 4; ++ns)
        acc[ms][ns] = MFMA16(af[ms], bfr[ns], acc[ms][ns]);
  }

  unsigned short* __restrict__ Db = D + (size_t)b * EMB * EMB;
#pragma unroll
  for (int ms = 0; ms < 4; ++ms)
#pragma unroll
    for (int ns = 0; ns < 4; ++ns)
#pragma unroll
      for (int r = 0; r < 4; ++r) {
        const int row = m0 + wr + ms*16 + ((lane >> 4) * 4) + r;
        const int col = n0 + wc + ns*16 + (lane & 15);
        Db[(size_t)row * EMB + col] = f2bf(acc[ms][ns][r]);
      }
}

// ---------------------------------------------------------------------------
// K3c: e[b] = C_b @ bv + bo.  grid 32*16 (32 rows each), block 256.
// ---------------------------------------------------------------------------
__global__ __launch_bounds__(256) void k3c_e(const unsigned short* __restrict__ C,
                                             const float* __restrict__ bv,
                                             const float* __restrict__ bo,
                                             float* __restrict__ evec) {
  const int blk = blockIdx.x;
  const int b = blk >> 4;
  const int g = blk & 15;
  const int tid  = threadIdx.x;
  const int lane = tid & 63;
  const int wave = tid >> 6;

  __shared__ float BV[EMB];
  for (int i = tid; i < EMB; i += 256) BV[i] = bv[i];
  __syncthreads();

  const unsigned short* __restrict__ Cb = C + (size_t)b * EMB * EMB;
#pragma unroll
  for (int p = 0; p < 8; ++p) {
    const int row = g*32 + wave*8 + p;
    const unsigned short* cr = &Cb[(size_t)row * EMB + lane * 8];
    const float* bvp = &BV[lane * 8];
    ushort4 v0 = *(const ushort4*)&cr[0];
    ushort4 v1 = *(const ushort4*)&cr[4];
    float a = bf2f(v0.x)*bvp[0] + bf2f(v0.y)*bvp[1] + bf2f(v0.z)*bvp[2] + bf2f(v0.w)*bvp[3]
            + bf2f(v1.x)*bvp[4] + bf2f(v1.y)*bvp[5] + bf2f(v1.z)*bvp[6] + bf2f(v1.w)*bvp[7];
#pragma unroll
    for (int m = 1; m < 64; m <<= 1) a += __shfl_xor(a, m);
    if (lane == 0) evec[b * EMB + row] = a + bo[row];
  }
}

// ---------------------------------------------------------------------------
// K4: out[b] = x_b @ D_b^T + e_b.  grid 32*32*4, block 256. BT-gemm, K=512.
// ---------------------------------------------------------------------------
__global__ __launch_bounds__(256) void k4_out(const float* __restrict__ x,
                                              const unsigned short* __restrict__ D,
                                              const float* __restrict__ evec,
                                              float* __restrict__ out) {
  const int blk = blockIdx.x;
  const int b  = blk >> 7;
  const int mt = (blk >> 2) & 31;
  const int nt = blk & 3;
  const int m0 = mt * 128, n0 = nt * 128;
  const float* __restrict__ xb = x + (size_t)b * SEQ * EMB;
  const unsigned short* __restrict__ Db = D + (size_t)b * EMB * EMB;

  __shared__ unsigned short LA[128][40];
  __shared__ unsigned short LB[128][40];

  const int tid  = threadIdx.x;
  const int lane = tid & 63;
  const int wave = tid >> 6;
  const int wr = (wave >> 1) * 64;
  const int wc = (wave & 1) * 64;

  f32x4 acc[4][4];
#pragma unroll
  for (int i = 0; i < 4; ++i)
#pragma unroll
    for (int j = 0; j < 4; ++j) acc[i][j] = (f32x4){0.f, 0.f, 0.f, 0.f};

  const int rA = tid >> 3, fgA = tid & 7;

  for (int k0 = 0; k0 < EMB; k0 += 32) {
    __syncthreads();
#pragma unroll
    for (int it = 0; it < 4; ++it) {
      const int r = rA + it * 32;
      const float4 v = *(const float4*)&xb[(size_t)(m0 + r) * EMB + k0 + fgA * 4];
      uint2 u; u.x = cvtpk(v.x, v.y); u.y = cvtpk(v.z, v.w);
      *(uint2*)&LA[r][fgA * 4] = u;
      *(ushort4*)&LB[r][fgA * 4] = *(const ushort4*)&Db[(size_t)(n0 + r) * EMB + k0 + fgA * 4];
    }
    __syncthreads();
    bf16x8 af[4], bfr[4];
#pragma unroll
    for (int ms = 0; ms < 4; ++ms)
      af[ms] = *(const bf16x8*)&LA[wr + ms*16 + (lane & 15)][(lane >> 4) * 8];
#pragma unroll
    for (int ns = 0; ns < 4; ++ns)
      bfr[ns] = *(const bf16x8*)&LB[wc + ns*16 + (lane & 15)][(lane >> 4) * 8];
#pragma unroll
    for (int ms = 0; ms < 4; ++ms)
#pragma unroll
      for (int ns = 0; ns < 4; ++ns)
        acc[ms][ns] = MFMA16(af[ms], bfr[ns], acc[ms][ns]);
  }

#pragma unroll
  for (int ms = 0; ms < 4; ++ms)
#pragma unroll
    for (int ns = 0; ns < 4; ++ns)
#pragma unroll
      for (int r = 0; r < 4; ++r) {
        const int row = m0 + wr + ms*16 + ((lane >> 4) * 4) + r;
        const int col = n0 + wc + ns*16 + (lane & 15);
        out[((size_t)b * SEQ + row) * EMB + col] = acc[ms][ns][r] + evec[b * EMB + col];
      }
}

// ---------------------------------------------------------------------------
extern "C" void kernel_launch(void* const* d_in, const int* in_sizes, int n_in,
                              void* d_out, int out_size, void* d_ws, size_t ws_size,
                              hipStream_t stream) {
  (void)in_sizes; (void)n_in; (void)out_size; (void)ws_size;
  const float* x  = (const float*)d_in[0];
  const float* Wq = (const float*)d_in[1];
  const float* bq = (const float*)d_in[2];
  const float* Wk = (const float*)d_in[3];
  const float* bk = (const float*)d_in[4];
  const float* Wv = (const float*)d_in[5];
  const float* bv = (const float*)d_in[6];
  const float* Wo = (const float*)d_in[7];
  const float* bo = (const float*)d_in[8];
  float* out = (float*)d_out;

  char* ws = (char*)d_ws;
  // Region layout (bytes). G dies after k2a; C/D reuse its region.
  float*          G    = (float*)(ws + 0);                     // 32 MB
  unsigned short* Cm   = (unsigned short*)(ws + 0);            // 16 MB (after G dead)
  unsigned short* Dm   = (unsigned short*)(ws + (16u << 20));  // 16 MB
  float*          A    = (float*)(ws + (32u << 20));           // 32 MB
  unsigned short* attn = (unsigned short*)(ws + (64u << 20));  // 2 MB
  float*          sv   = (float*)(ws + (66u << 20));           // 64 KB
  float*          ev   = (float*)(ws + (66u << 20) + (64u << 10)); // 64 KB

  hipLaunchKernelGGL(k1_gram,    dim3(BATCH * 16),  dim3(256), 0, stream, x, G, sv);
  hipLaunchKernelGGL(k2a_wqg,    dim3(BATCH * 16),  dim3(256), 0, stream, Wq, G, A);
  hipLaunchKernelGGL(k2b_logits, dim3(BATCH * 8),   dim3(256), 0, stream, A, Wq, Wk, bq, bk, sv, attn);
  hipLaunchKernelGGL(k3a_c,      dim3(BATCH * 32),  dim3(256), 0, stream, Wo, attn, Cm);
  hipLaunchKernelGGL(k3b_d,      dim3(BATCH * 16),  dim3(256), 0, stream, Cm, Wv, Dm);
  hipLaunchKernelGGL(k3c_e,      dim3(BATCH * 16),  dim3(256), 0, stream, Cm, bv, bo, ev);
  hipLaunchKernelGGL(k4_out,     dim3(BATCH * 128), dim3(256), 0, stream, x, Dm, ev, out);
}

// Round 3
// 452.619 us; speedup vs baseline: 2.2164x; 1.2429x over previous
//
#include <hip/hip_runtime.h>
#include <hip/hip_bf16.h>
#include <stdint.h>

#define BATCH 32
#define SEQ   4096
#define EMB   512
#define HEADS 8
#define HD    64
#define SCALE 0.125f   // 1/sqrt(64)

typedef __attribute__((ext_vector_type(8))) short bf16x8;
typedef __attribute__((ext_vector_type(4))) float f32x4;

__device__ __forceinline__ unsigned short f2bf(float f) {
    union { float f; unsigned int u; } v; v.f = f;
    unsigned int u = v.u;
    return (unsigned short)((u + 0x7FFFu + ((u >> 16) & 1u)) >> 16);
}
__device__ __forceinline__ float bf2f(unsigned short h) {
    union { unsigned int u; float f; } v; v.u = ((unsigned int)h) << 16;
    return v.f;
}
// HW packed fp32->bf16 (RNE): first arg -> bits[15:0], second -> bits[31:16]
__device__ __forceinline__ unsigned int cvtpk(float lo, float hi) {
    unsigned int r;
    asm("v_cvt_pk_bf16_f32 %0, %1, %2" : "=v"(r) : "v"(lo), "v"(hi));
    return r;
}
__device__ __forceinline__ float lo_as_f(unsigned int p) {
    union { unsigned int u; float f; } v; v.u = p << 16; return v.f;
}
__device__ __forceinline__ float hi_as_f(unsigned int p) {
    union { unsigned int u; float f; } v; v.u = p & 0xFFFF0000u; return v.f;
}

#define MFMA16(a, b, c) __builtin_amdgcn_mfma_f32_16x16x32_bf16((a), (b), (c), 0, 0, 0)

union F4 { float4 v; float f[4]; };

// ---------------------------------------------------------------------------
// K1: G[b] = x_b^T x_b (fp32), s[b] = column sums (diag blocks), and (XBF)
// xbf = bf16(x) written by diag blocks (each covers its 128-col panel once).
// T14 ordering: issue next-tile loads before MFMA; cvt+ds_write after.
// XCD swizzle: all 16 blocks of a batch on one XCD.
// ---------------------------------------------------------------------------
template <bool XBF>
__global__ __launch_bounds__(256) void k1_gram(const float* __restrict__ x,
                                               float* __restrict__ G,
                                               float* __restrict__ s,
                                               unsigned short* __restrict__ xbf) {
  const int bid = blockIdx.x;                 // nwg = 512
  const int wk  = (bid & 7) * 64 + (bid >> 3);
  const int b  = wk >> 4;
  const int mt = (wk >> 2) & 3;
  const int nt = wk & 3;
  const int m0 = mt * 128, n0 = nt * 128;
  const bool diag = (mt == nt);
  const float* __restrict__ xb = x + (size_t)b * SEQ * EMB;

  __shared__ unsigned short LA[32 * 136];
  __shared__ unsigned short LB[32 * 136];
  __shared__ float SR[128][8];

  const int tid  = threadIdx.x;
  const int lane = tid & 63;
  const int wave = tid >> 6;
  const int wr = (wave >> 1) * 64;
  const int wc = (wave & 1) * 64;

  const int fg   = tid & 31;   // e-group: e = fg*4 + i
  const int kgrp = tid >> 5;   // k-group: k = kgrp*4 + j

  f32x4 acc[4][4];
#pragma unroll
  for (int i = 0; i < 4; ++i)
#pragma unroll
    for (int j = 0; j < 4; ++j) acc[i][j] = (f32x4){0.f, 0.f, 0.f, 0.f};

  float sacc[4] = {0.f, 0.f, 0.f, 0.f};
  const unsigned short* __restrict__ Bsrc = diag ? LA : LB;

  F4 a0, a1, a2, a3, b0, b1, b2, b3;

  // prologue: load k0 = 0
  {
    const float* pA = &xb[(size_t)(kgrp * 4) * EMB + m0 + fg * 4];
    a0.v = *(const float4*)pA;
    a1.v = *(const float4*)(pA + EMB);
    a2.v = *(const float4*)(pA + 2 * EMB);
    a3.v = *(const float4*)(pA + 3 * EMB);
    if (!diag) {
      const float* pB = &xb[(size_t)(kgrp * 4) * EMB + n0 + fg * 4];
      b0.v = *(const float4*)pB;
      b1.v = *(const float4*)(pB + EMB);
      b2.v = *(const float4*)(pB + 2 * EMB);
      b3.v = *(const float4*)(pB + 3 * EMB);
    }
  }

  for (int k0 = 0; k0 < SEQ; k0 += 32) {
    // pack current regs
    uint2 wA[4], wB[4], xr[4];
#pragma unroll
    for (int i = 0; i < 4; ++i) {
      const float e0 = a0.f[i], e1 = a1.f[i], e2 = a2.f[i], e3 = a3.f[i];
      if (diag) sacc[i] += (e0 + e1) + (e2 + e3);
      wA[i].x = cvtpk(e0, e1); wA[i].y = cvtpk(e2, e3);
    }
    if (diag) {
      if (XBF) {
        xr[0].x = cvtpk(a0.f[0], a0.f[1]); xr[0].y = cvtpk(a0.f[2], a0.f[3]);
        xr[1].x = cvtpk(a1.f[0], a1.f[1]); xr[1].y = cvtpk(a1.f[2], a1.f[3]);
        xr[2].x = cvtpk(a2.f[0], a2.f[1]); xr[2].y = cvtpk(a2.f[2], a2.f[3]);
        xr[3].x = cvtpk(a3.f[0], a3.f[1]); xr[3].y = cvtpk(a3.f[2], a3.f[3]);
      }
    } else {
#pragma unroll
      for (int i = 0; i < 4; ++i) {
        wB[i].x = cvtpk(b0.f[i], b1.f[i]); wB[i].y = cvtpk(b2.f[i], b3.f[i]);
      }
    }

    __syncthreads();   // previous iter's frag reads done
#pragma unroll
    for (int i = 0; i < 4; ++i)
      *(uint2*)&LA[fg * 136 + i * 32 + kgrp * 4] = wA[i];
    if (diag) {
      if (XBF) {
        unsigned short* xp = &xbf[((size_t)b * SEQ + k0 + kgrp * 4) * EMB + m0 + fg * 4];
#pragma unroll
        for (int j = 0; j < 4; ++j)
          *(uint2*)&xp[(size_t)j * EMB] = xr[j];
      }
    } else {
#pragma unroll
      for (int i = 0; i < 4; ++i)
        *(uint2*)&LB[fg * 136 + i * 32 + kgrp * 4] = wB[i];
    }
    __syncthreads();

    // issue next-tile loads (fly under MFMA)
    if (k0 + 32 < SEQ) {
      const float* pA = &xb[(size_t)(k0 + 32 + kgrp * 4) * EMB + m0 + fg * 4];
      a0.v = *(const float4*)pA;
      a1.v = *(const float4*)(pA + EMB);
      a2.v = *(const float4*)(pA + 2 * EMB);
      a3.v = *(const float4*)(pA + 3 * EMB);
      if (!diag) {
        const float* pB = &xb[(size_t)(k0 + 32 + kgrp * 4) * EMB + n0 + fg * 4];
        b0.v = *(const float4*)pB;
        b1.v = *(const float4*)(pB + EMB);
        b2.v = *(const float4*)(pB + 2 * EMB);
        b3.v = *(const float4*)(pB + 3 * EMB);
      }
    }

    bf16x8 af[4], bfr[4];
    const int er = lane & 15, kb = (lane >> 4) * 8;
#pragma unroll
    for (int ms = 0; ms < 4; ++ms) {
      const int e = wr + ms * 16 + er;
      af[ms] = *(const bf16x8*)&LA[(e >> 2) * 136 + (e & 3) * 32 + kb];
    }
#pragma unroll
    for (int ns = 0; ns < 4; ++ns) {
      const int e = wc + ns * 16 + er;
      bfr[ns] = *(const bf16x8*)&Bsrc[(e >> 2) * 136 + (e & 3) * 32 + kb];
    }
#pragma unroll
    for (int ms = 0; ms < 4; ++ms)
#pragma unroll
      for (int ns = 0; ns < 4; ++ns)
        acc[ms][ns] = MFMA16(af[ms], bfr[ns], acc[ms][ns]);
  }

  float* __restrict__ Gb = G + (size_t)b * EMB * EMB;
#pragma unroll
  for (int ms = 0; ms < 4; ++ms)
#pragma unroll
    for (int ns = 0; ns < 4; ++ns)
#pragma unroll
      for (int r = 0; r < 4; ++r) {
        const int row = m0 + wr + ms * 16 + ((lane >> 4) * 4) + r;
        const int col = n0 + wc + ns * 16 + (lane & 15);
        Gb[(size_t)row * EMB + col] = acc[ms][ns][r];
      }

  if (diag) {
    __syncthreads();
#pragma unroll
    for (int i = 0; i < 4; ++i) SR[fg * 4 + i][kgrp] = sacc[i];
    __syncthreads();
    if (tid < 128) {
      float v = 0.f;
#pragma unroll
      for (int j = 0; j < 8; ++j) v += SR[tid][j];
      s[b * EMB + m0 + tid] = v;
    }
  }
}

// ---------------------------------------------------------------------------
// K2a: A[b] = Wq @ G_b (fp32 out). B uses G's symmetry (direct rows), hi/lo
// split. XCD swizzle added. grid 32*16, block 256.
// ---------------------------------------------------------------------------
__global__ __launch_bounds__(256) void k2a_wqg(const float* __restrict__ Wq,
                                               const float* __restrict__ G,
                                               float* __restrict__ A) {
  const int bid = blockIdx.x;                 // nwg = 512
  const int wk  = (bid & 7) * 64 + (bid >> 3);
  const int b  = wk >> 4;
  const int mt = (wk >> 2) & 3;
  const int nt = wk & 3;
  const int m0 = mt * 128, n0 = nt * 128;
  const float* __restrict__ Gb = G + (size_t)b * EMB * EMB;

  __shared__ unsigned short LA[128][40];
  __shared__ unsigned short LBhi[128][40];
  __shared__ unsigned short LBlo[128][40];

  const int tid  = threadIdx.x;
  const int lane = tid & 63;
  const int wave = tid >> 6;
  const int wr = (wave >> 1) * 64;
  const int wc = (wave & 1) * 64;

  f32x4 acc[4][4];
#pragma unroll
  for (int i = 0; i < 4; ++i)
#pragma unroll
    for (int j = 0; j < 4; ++j) acc[i][j] = (f32x4){0.f, 0.f, 0.f, 0.f};

  const int rA = tid >> 3, fgA = tid & 7;

  for (int k0 = 0; k0 < EMB; k0 += 32) {
    __syncthreads();
#pragma unroll
    for (int it = 0; it < 4; ++it) {   // A: Wq rows, direct
      const int r = rA + it * 32;
      const float4 v = *(const float4*)&Wq[(size_t)(m0 + r) * EMB + k0 + fgA * 4];
      uint2 u; u.x = cvtpk(v.x, v.y); u.y = cvtpk(v.z, v.w);
      *(uint2*)&LA[r][fgA * 4] = u;
    }
#pragma unroll
    for (int it = 0; it < 4; ++it) {   // B: G rows (symmetric), hi/lo split
      const int r = rA + it * 32;
      const float4 v = *(const float4*)&Gb[(size_t)(n0 + r) * EMB + k0 + fgA * 4];
      uint2 h; h.x = cvtpk(v.x, v.y); h.y = cvtpk(v.z, v.w);
      uint2 l;
      l.x = cvtpk(v.x - lo_as_f(h.x), v.y - hi_as_f(h.x));
      l.y = cvtpk(v.z - lo_as_f(h.y), v.w - hi_as_f(h.y));
      *(uint2*)&LBhi[r][fgA * 4] = h;
      *(uint2*)&LBlo[r][fgA * 4] = l;
    }
    __syncthreads();
    bf16x8 af[4], bh[4], bl[4];
#pragma unroll
    for (int ms = 0; ms < 4; ++ms)
      af[ms] = *(const bf16x8*)&LA[wr + ms*16 + (lane & 15)][(lane >> 4) * 8];
#pragma unroll
    for (int ns = 0; ns < 4; ++ns) {
      bh[ns] = *(const bf16x8*)&LBhi[wc + ns*16 + (lane & 15)][(lane >> 4) * 8];
      bl[ns] = *(const bf16x8*)&LBlo[wc + ns*16 + (lane & 15)][(lane >> 4) * 8];
    }
#pragma unroll
    for (int ms = 0; ms < 4; ++ms)
#pragma unroll
      for (int ns = 0; ns < 4; ++ns) {
        acc[ms][ns] = MFMA16(af[ms], bh[ns], acc[ms][ns]);
        acc[ms][ns] = MFMA16(af[ms], bl[ns], acc[ms][ns]);
      }
  }

  float* __restrict__ Ab = A + (size_t)b * EMB * EMB;
#pragma unroll
  for (int ms = 0; ms < 4; ++ms)
#pragma unroll
    for (int ns = 0; ns < 4; ++ns)
#pragma unroll
      for (int r = 0; r < 4; ++r) {
        const int row = m0 + wr + ms*16 + ((lane >> 4) * 4) + r;
        const int col = n0 + wc + ns*16 + (lane & 15);
        Ab[(size_t)row * EMB + col] = acc[ms][ns][r];
      }
}

// ---------------------------------------------------------------------------
// K2b: per (b,h): logits = A_h @ Wk_h^T + bias terms, *1/8, softmax rows,
// store attn bf16 (64x64). grid 256 (b*8+h), block 256.
// ---------------------------------------------------------------------------
__global__ __launch_bounds__(256) void k2b_logits(const float* __restrict__ A,
                                                  const float* __restrict__ Wq,
                                                  const float* __restrict__ Wk,
                                                  const float* __restrict__ bq,
                                                  const float* __restrict__ bk,
                                                  const float* __restrict__ s,
                                                  unsigned short* __restrict__ attn) {
  const int blk = blockIdx.x;
  const int b = blk >> 3;
  const int h = blk & 7;
  const float* __restrict__ Ab = A + (size_t)b * EMB * EMB + (size_t)h * HD * EMB;
  const float* __restrict__ sb = s + b * EMB;

  __shared__ unsigned short LAhi[64][40];
  __shared__ unsigned short LAlo[64][40];
  __shared__ unsigned short LB[64][40];
  __shared__ float U[HD], W[HD];

  const int tid  = threadIdx.x;
  const int lane = tid & 63;
  const int wave = tid >> 6;

  // u = Wq_h @ s, w = Wk_h @ s
  if (tid < 128) {
    const int q = tid & 63;
    const float* __restrict__ wrow = (tid < 64 ? Wq : Wk) + (size_t)(h * HD + q) * EMB;
    float a = 0.f;
    for (int i = 0; i < EMB; i += 4) {
      const float4 wv = *(const float4*)&wrow[i];
      const float4 sv = *(const float4*)&sb[i];
      a += wv.x*sv.x + wv.y*sv.y + wv.z*sv.z + wv.w*sv.w;
    }
    if (tid < 64) U[q] = a; else W[q] = a;
  }

  f32x4 acc[4];
#pragma unroll
  for (int i = 0; i < 4; ++i) acc[i] = (f32x4){0.f, 0.f, 0.f, 0.f};

  const int r8 = tid >> 3, fg8 = tid & 7;

  for (int k0 = 0; k0 < EMB; k0 += 32) {
    __syncthreads();
#pragma unroll
    for (int it = 0; it < 2; ++it) {
      const int r = r8 + it * 32;
      const float4 v = *(const float4*)&Ab[(size_t)r * EMB + k0 + fg8 * 4];
      uint2 h2; h2.x = cvtpk(v.x, v.y); h2.y = cvtpk(v.z, v.w);
      uint2 l2;
      l2.x = cvtpk(v.x - lo_as_f(h2.x), v.y - hi_as_f(h2.x));
      l2.y = cvtpk(v.z - lo_as_f(h2.y), v.w - hi_as_f(h2.y));
      *(ushort4*)&LAhi[r][fg8*4] = *(ushort4*)&h2;
      *(ushort4*)&LAlo[r][fg8*4] = *(ushort4*)&l2;
      const float4 wv = *(const float4*)&Wk[(size_t)(h*HD + r) * EMB + k0 + fg8 * 4];
      uint2 ub; ub.x = cvtpk(wv.x, wv.y); ub.y = cvtpk(wv.z, wv.w);
      *(ushort4*)&LB[r][fg8*4] = *(ushort4*)&ub;
    }
    __syncthreads();
    const bf16x8 ah = *(const bf16x8*)&LAhi[wave*16 + (lane & 15)][(lane >> 4) * 8];
    const bf16x8 al = *(const bf16x8*)&LAlo[wave*16 + (lane & 15)][(lane >> 4) * 8];
#pragma unroll
    for (int ns = 0; ns < 4; ++ns) {
      const bf16x8 bb = *(const bf16x8*)&LB[ns*16 + (lane & 15)][(lane >> 4) * 8];
      acc[ns] = MFMA16(ah, bb, acc[ns]);
      acc[ns] = MFMA16(al, bb, acc[ns]);
    }
  }

  // epilogue: bias + scale + softmax over cols (axis k')
  const int colb = lane & 15;
  float bkv[4], wv_[4];
#pragma unroll
  for (int ns = 0; ns < 4; ++ns) {
    bkv[ns] = bk[h*HD + ns*16 + colb];
    wv_[ns] = W[ns*16 + colb];
  }
  unsigned short* __restrict__ ab = attn + (size_t)(b * HEADS + h) * HD * HD;
#pragma unroll
  for (int r = 0; r < 4; ++r) {
    const int row = wave*16 + ((lane >> 4) * 4) + r;
    const float bqv = bq[h*HD + row];
    const float uv  = U[row];
    float vals[4];
#pragma unroll
    for (int ns = 0; ns < 4; ++ns)
      vals[ns] = (acc[ns][r] + uv * bkv[ns] + bqv * wv_[ns] + 4096.f * bqv * bkv[ns]) * SCALE;
    float mx = fmaxf(fmaxf(vals[0], vals[1]), fmaxf(vals[2], vals[3]));
#pragma unroll
    for (int m = 1; m < 16; m <<= 1) mx = fmaxf(mx, __shfl_xor(mx, m));
    float sum = 0.f;
#pragma unroll
    for (int ns = 0; ns < 4; ++ns) { vals[ns] = expf(vals[ns] - mx); sum += vals[ns]; }
#pragma unroll
    for (int m = 1; m < 16; m <<= 1) sum += __shfl_xor(sum, m);
    const float inv = 1.f / sum;
#pragma unroll
    for (int ns = 0; ns < 4; ++ns)
      ab[(size_t)row * HD + ns*16 + colb] = f2bf(vals[ns] * inv);
  }
}

// ---------------------------------------------------------------------------
// K3a: C[b][:, h*64..] = Wo[:, h*64..] @ attn_h   (bf16 out). K=64.
// grid 32*8*4 (b,h,mt), block 256.
// ---------------------------------------------------------------------------
__global__ __launch_bounds__(256) void k3a_c(const float* __restrict__ Wo,
                                             const unsigned short* __restrict__ attn,
                                             unsigned short* __restrict__ C) {
  const int blk = blockIdx.x;
  const int b  = blk >> 5;
  const int h  = (blk >> 2) & 7;
  const int mt = blk & 3;
  const int m0 = mt * 128;

  __shared__ unsigned short LA[128][72];
  __shared__ unsigned short LB[64][72];

  const int tid  = threadIdx.x;
  const int lane = tid & 63;
  const int wave = tid >> 6;

  {
    const int r  = tid >> 4;   // 0..15
    const int fg = tid & 15;
#pragma unroll
    for (int it = 0; it < 8; ++it) {
      const int rr = r + it * 16;
      const float4 v = *(const float4*)&Wo[(size_t)(m0 + rr) * EMB + h*HD + fg * 4];
      uint2 u; u.x = cvtpk(v.x, v.y); u.y = cvtpk(v.z, v.w);
      *(uint2*)&LA[rr][fg * 4] = u;
    }
  }
  {
    const unsigned short* __restrict__ ab = attn + (size_t)(b * HEADS + h) * HD * HD;
#pragma unroll
    for (int it = 0; it < 16; ++it) {
      const int f  = tid + 256 * it;
      const int q  = f >> 6;
      const int kp = f & 63;
      LB[kp][q] = ab[q * HD + kp];   // transpose
    }
  }
  __syncthreads();

  f32x4 acc[2][4];
#pragma unroll
  for (int i = 0; i < 2; ++i)
#pragma unroll
    for (int j = 0; j < 4; ++j) acc[i][j] = (f32x4){0.f, 0.f, 0.f, 0.f};

#pragma unroll
  for (int kk = 0; kk < 2; ++kk) {
    bf16x8 af[2], bfr[4];
#pragma unroll
    for (int ms = 0; ms < 2; ++ms)
      af[ms] = *(const bf16x8*)&LA[wave*32 + ms*16 + (lane & 15)][kk*32 + (lane >> 4) * 8];
#pragma unroll
    for (int ns = 0; ns < 4; ++ns)
      bfr[ns] = *(const bf16x8*)&LB[ns*16 + (lane & 15)][kk*32 + (lane >> 4) * 8];
#pragma unroll
    for (int ms = 0; ms < 2; ++ms)
#pragma unroll
      for (int ns = 0; ns < 4; ++ns)
        acc[ms][ns] = MFMA16(af[ms], bfr[ns], acc[ms][ns]);
  }

  unsigned short* __restrict__ Cb = C + (size_t)b * EMB * EMB;
#pragma unroll
  for (int ms = 0; ms < 2; ++ms)
#pragma unroll
    for (int ns = 0; ns < 4; ++ns)
#pragma unroll
      for (int r = 0; r < 4; ++r) {
        const int row = m0 + wave*32 + ms*16 + ((lane >> 4) * 4) + r;
        const int col = h*HD + ns*16 + (lane & 15);
        Cb[(size_t)row * EMB + col] = f2bf(acc[ms][ns][r]);
      }
}

// ---------------------------------------------------------------------------
// K3b: D[b] = C_b @ Wv  (bf16 out). grid 32*16, block 256. XCD swizzle.
// ---------------------------------------------------------------------------
__global__ __launch_bounds__(256) void k3b_d(const unsigned short* __restrict__ C,
                                             const float* __restrict__ Wv,
                                             unsigned short* __restrict__ D) {
  const int bid = blockIdx.x;                 // nwg = 512
  const int wk  = (bid & 7) * 64 + (bid >> 3);
  const int b  = wk >> 4;
  const int mt = (wk >> 2) & 3;
  const int nt = wk & 3;
  const int m0 = mt * 128, n0 = nt * 128;
  const unsigned short* __restrict__ Cb = C + (size_t)b * EMB * EMB;

  __shared__ unsigned short LA[128][40];
  __shared__ unsigned short LB[128][40];

  const int tid  = threadIdx.x;
  const int lane = tid & 63;
  const int wave = tid >> 6;
  const int wr = (wave >> 1) * 64;
  const int wc = (wave & 1) * 64;

  f32x4 acc[4][4];
#pragma unroll
  for (int i = 0; i < 4; ++i)
#pragma unroll
    for (int j = 0; j < 4; ++j) acc[i][j] = (f32x4){0.f, 0.f, 0.f, 0.f};

  const int kl = tid >> 5, fgB = tid & 31;
  const int rA = tid >> 3, fgA = tid & 7;

  for (int k0 = 0; k0 < EMB; k0 += 32) {
    __syncthreads();
#pragma unroll
    for (int it = 0; it < 4; ++it) {
      const int r = rA + it * 32;
      *(ushort4*)&LA[r][fgA*4] = *(const ushort4*)&Cb[(size_t)(m0 + r) * EMB + k0 + fgA * 4];
    }
#pragma unroll
    for (int it = 0; it < 4; ++it) {
      const int k = kl + it * 8;
      const float4 v = *(const float4*)&Wv[(size_t)(k0 + k) * EMB + n0 + fgB * 4];
      LB[fgB*4+0][k] = f2bf(v.x);
      LB[fgB*4+1][k] = f2bf(v.y);
      LB[fgB*4+2][k] = f2bf(v.z);
      LB[fgB*4+3][k] = f2bf(v.w);
    }
    __syncthreads();
    bf16x8 af[4], bfr[4];
#pragma unroll
    for (int ms = 0; ms < 4; ++ms)
      af[ms] = *(const bf16x8*)&LA[wr + ms*16 + (lane & 15)][(lane >> 4) * 8];
#pragma unroll
    for (int ns = 0; ns < 4; ++ns)
      bfr[ns] = *(const bf16x8*)&LB[wc + ns*16 + (lane & 15)][(lane >> 4) * 8];
#pragma unroll
    for (int ms = 0; ms < 4; ++ms)
#pragma unroll
      for (int ns = 0; ns < 4; ++ns)
        acc[ms][ns] = MFMA16(af[ms], bfr[ns], acc[ms][ns]);
  }

  unsigned short* __restrict__ Db = D + (size_t)b * EMB * EMB;
#pragma unroll
  for (int ms = 0; ms < 4; ++ms)
#pragma unroll
    for (int ns = 0; ns < 4; ++ns)
#pragma unroll
      for (int r = 0; r < 4; ++r) {
        const int row = m0 + wr + ms*16 + ((lane >> 4) * 4) + r;
        const int col = n0 + wc + ns*16 + (lane & 15);
        Db[(size_t)row * EMB + col] = f2bf(acc[ms][ns][r]);
      }
}

// ---------------------------------------------------------------------------
// K3c: e[b] = C_b @ bv + bo.  grid 32*16 (32 rows each), block 256.
// ---------------------------------------------------------------------------
__global__ __launch_bounds__(256) void k3c_e(const unsigned short* __restrict__ C,
                                             const float* __restrict__ bv,
                                             const float* __restrict__ bo,
                                             float* __restrict__ evec) {
  const int blk = blockIdx.x;
  const int b = blk >> 4;
  const int g = blk & 15;
  const int tid  = threadIdx.x;
  const int lane = tid & 63;
  const int wave = tid >> 6;

  __shared__ float BV[EMB];
  for (int i = tid; i < EMB; i += 256) BV[i] = bv[i];
  __syncthreads();

  const unsigned short* __restrict__ Cb = C + (size_t)b * EMB * EMB;
#pragma unroll
  for (int p = 0; p < 8; ++p) {
    const int row = g*32 + wave*8 + p;
    const unsigned short* cr = &Cb[(size_t)row * EMB + lane * 8];
    const float* bvp = &BV[lane * 8];
    ushort4 v0 = *(const ushort4*)&cr[0];
    ushort4 v1 = *(const ushort4*)&cr[4];
    float a = bf2f(v0.x)*bvp[0] + bf2f(v0.y)*bvp[1] + bf2f(v0.z)*bvp[2] + bf2f(v0.w)*bvp[3]
            + bf2f(v1.x)*bvp[4] + bf2f(v1.y)*bvp[5] + bf2f(v1.z)*bvp[6] + bf2f(v1.w)*bvp[7];
#pragma unroll
    for (int m = 1; m < 64; m <<= 1) a += __shfl_xor(a, m);
    if (lane == 0) evec[b * EMB + row] = a + bo[row];
  }
}

// ---------------------------------------------------------------------------
// K4: out[b] = x_b @ D_b^T + e_b.  grid 32*32*4, block 256. K=512.
// XBF: A staged from bf16 xbf (no cvt). T14 issue-early loads. XCD swizzle.
// ---------------------------------------------------------------------------
template <bool XBF>
__global__ __launch_bounds__(256) void k4_out(const float* __restrict__ x,
                                              const unsigned short* __restrict__ xbf,
                                              const unsigned short* __restrict__ D,
                                              const float* __restrict__ evec,
                                              float* __restrict__ out) {
  const int bid = blockIdx.x;                  // nwg = 4096
  const int wk  = (bid & 7) * 512 + (bid >> 3);
  const int b  = wk >> 7;
  const int mt = (wk >> 2) & 31;
  const int nt = wk & 3;
  const int m0 = mt * 128, n0 = nt * 128;
  const float* __restrict__ xb = x + (size_t)b * SEQ * EMB;
  const unsigned short* __restrict__ xbb = xbf + (size_t)b * SEQ * EMB;
  const unsigned short* __restrict__ Db = D + (size_t)b * EMB * EMB;

  __shared__ unsigned short LA[128][40];
  __shared__ unsigned short LB[128][40];

  const int tid  = threadIdx.x;
  const int lane = tid & 63;
  const int wave = tid >> 6;
  const int wr = (wave >> 1) * 64;
  const int wc = (wave & 1) * 64;

  f32x4 acc[4][4];
#pragma unroll
  for (int i = 0; i < 4; ++i)
#pragma unroll
    for (int j = 0; j < 4; ++j) acc[i][j] = (f32x4){0.f, 0.f, 0.f, 0.f};

  const int rA = tid >> 3, fgA = tid & 7;

  F4 fa[4];
  ushort4 ua[4], ub[4];

  // prologue loads (k0 = 0)
#pragma unroll
  for (int it = 0; it < 4; ++it) {
    const int r = rA + it * 32;
    if (XBF) ua[it] = *(const ushort4*)&xbb[(size_t)(m0 + r) * EMB + fgA * 4];
    else     fa[it].v = *(const float4*)&xb[(size_t)(m0 + r) * EMB + fgA * 4];
    ub[it] = *(const ushort4*)&Db[(size_t)(n0 + r) * EMB + fgA * 4];
  }

  for (int k0 = 0; k0 < EMB; k0 += 32) {
    uint2 wA[4];
    if (!XBF) {
#pragma unroll
      for (int it = 0; it < 4; ++it) {
        wA[it].x = cvtpk(fa[it].f[0], fa[it].f[1]);
        wA[it].y = cvtpk(fa[it].f[2], fa[it].f[3]);
      }
    }
    __syncthreads();
#pragma unroll
    for (int it = 0; it < 4; ++it) {
      const int r = rA + it * 32;
      if (XBF) *(ushort4*)&LA[r][fgA * 4] = ua[it];
      else     *(uint2*)&LA[r][fgA * 4] = wA[it];
      *(ushort4*)&LB[r][fgA * 4] = ub[it];
    }
    __syncthreads();

    if (k0 + 32 < EMB) {
#pragma unroll
      for (int it = 0; it < 4; ++it) {
        const int r = rA + it * 32;
        if (XBF) ua[it] = *(const ushort4*)&xbb[(size_t)(m0 + r) * EMB + k0 + 32 + fgA * 4];
        else     fa[it].v = *(const float4*)&xb[(size_t)(m0 + r) * EMB + k0 + 32 + fgA * 4];
        ub[it] = *(const ushort4*)&Db[(size_t)(n0 + r) * EMB + k0 + 32 + fgA * 4];
      }
    }

    bf16x8 af[4], bfr[4];
#pragma unroll
    for (int ms = 0; ms < 4; ++ms)
      af[ms] = *(const bf16x8*)&LA[wr + ms*16 + (lane & 15)][(lane >> 4) * 8];
#pragma unroll
    for (int ns = 0; ns < 4; ++ns)
      bfr[ns] = *(const bf16x8*)&LB[wc + ns*16 + (lane & 15)][(lane >> 4) * 8];
#pragma unroll
    for (int ms = 0; ms < 4; ++ms)
#pragma unroll
      for (int ns = 0; ns < 4; ++ns)
        acc[ms][ns] = MFMA16(af[ms], bfr[ns], acc[ms][ns]);
  }

#pragma unroll
  for (int ms = 0; ms < 4; ++ms)
#pragma unroll
    for (int ns = 0; ns < 4; ++ns)
#pragma unroll
      for (int r = 0; r < 4; ++r) {
        const int row = m0 + wr + ms*16 + ((lane >> 4) * 4) + r;
        const int col = n0 + wc + ns*16 + (lane & 15);
        out[((size_t)b * SEQ + row) * EMB + col] = acc[ms][ns][r] + evec[b * EMB + col];
      }
}

// ---------------------------------------------------------------------------
extern "C" void kernel_launch(void* const* d_in, const int* in_sizes, int n_in,
                              void* d_out, int out_size, void* d_ws, size_t ws_size,
                              hipStream_t stream) {
  (void)in_sizes; (void)n_in; (void)out_size;
  const float* x  = (const float*)d_in[0];
  const float* Wq = (const float*)d_in[1];
  const float* bq = (const float*)d_in[2];
  const float* Wk = (const float*)d_in[3];
  const float* bk = (const float*)d_in[4];
  const float* Wv = (const float*)d_in[5];
  const float* bv = (const float*)d_in[6];
  const float* Wo = (const float*)d_in[7];
  const float* bo = (const float*)d_in[8];
  float* out = (float*)d_out;

  char* ws = (char*)d_ws;
  const size_t XBF_BYTES = (size_t)BATCH * SEQ * EMB * 2;   // 128 MiB
  const size_t NEED = XBF_BYTES + (48u << 20) + (2u << 20) + (256u << 10);
  const bool use_xbf = (ws_size >= NEED);

  unsigned short* xbf;
  float* G; unsigned short* Cm; unsigned short* Dm; float* A;
  unsigned short* attn; float* sv; float* ev;

  if (use_xbf) {
    xbf  = (unsigned short*)(ws + 0);                         // 128 MiB
    G    = (float*)(ws + XBF_BYTES);                          // 32 MiB (dies after k2a)
    Cm   = (unsigned short*)(ws + XBF_BYTES);                 // 16 MiB (reuses G)
    Dm   = (unsigned short*)(ws + XBF_BYTES + (16u << 20));   // 16 MiB
    A    = (float*)(ws + XBF_BYTES + (32u << 20));            // 32 MiB... wait
    // A must not overlap G (G live until k2a done, A written by k2a) -> A after G:
    A    = (float*)(ws + XBF_BYTES + (32u << 20));            // overlaps Dm region? no:
    // G: [XBF, XBF+32M). A: [XBF+32M, XBF+64M). C/D reuse G's region afterwards.
    Cm   = (unsigned short*)(ws + XBF_BYTES);
    Dm   = (unsigned short*)(ws + XBF_BYTES + (16u << 20));
    attn = (unsigned short*)(ws + XBF_BYTES + (64u << 20));   // 2 MiB
    sv   = (float*)(ws + XBF_BYTES + (66u << 20));
    ev   = (float*)(ws + XBF_BYTES + (66u << 20) + (64u << 10));
  } else {
    xbf  = (unsigned short*)(ws + 0);   // unused
    G    = (float*)(ws + 0);
    Cm   = (unsigned short*)(ws + 0);
    Dm   = (unsigned short*)(ws + (16u << 20));
    A    = (float*)(ws + (32u << 20));
    attn = (unsigned short*)(ws + (64u << 20));
    sv   = (float*)(ws + (66u << 20));
    ev   = (float*)(ws + (66u << 20) + (64u << 10));
  }

  if (use_xbf) {
    hipLaunchKernelGGL((k1_gram<true>),  dim3(BATCH * 16),  dim3(256), 0, stream, x, G, sv, xbf);
  } else {
    hipLaunchKernelGGL((k1_gram<false>), dim3(BATCH * 16),  dim3(256), 0, stream, x, G, sv, xbf);
  }
  hipLaunchKernelGGL(k2a_wqg,    dim3(BATCH * 16),  dim3(256), 0, stream, Wq, G, A);
  hipLaunchKernelGGL(k2b_logits, dim3(BATCH * 8),   dim3(256), 0, stream, A, Wq, Wk, bq, bk, sv, attn);
  hipLaunchKernelGGL(k3a_c,      dim3(BATCH * 32),  dim3(256), 0, stream, Wo, attn, Cm);
  hipLaunchKernelGGL(k3b_d,      dim3(BATCH * 16),  dim3(256), 0, stream, Cm, Wv, Dm);
  hipLaunchKernelGGL(k3c_e,      dim3(BATCH * 16),  dim3(256), 0, stream, Cm, bv, bo, ev);
  if (use_xbf) {
    hipLaunchKernelGGL((k4_out<true>),  dim3(BATCH * 128), dim3(256), 0, stream, x, xbf, Dm, ev, out);
  } else {
    hipLaunchKernelGGL((k4_out<false>), dim3(BATCH * 128), dim3(256), 0, stream, x, xbf, Dm, ev, out);
  }
}